// Round 22
// baseline (325.312 us; speedup 1.0000x reference)
//
#include <hip/hip_runtime.h>
#include <math.h>

namespace {

constexpr int BT  = 8 * 4096;   // 32768 tokens
constexpr int DIM = 1024;       // model dim
constexpr int NE  = 64;         // experts
constexpr int NS  = 8;          // slots per expert
constexpr int NP  = NE * NS;    // 512 total slots
constexpr int HID = 256;

typedef float f32x4 __attribute__((ext_vector_type(4)));
typedef __bf16 bf16x8 __attribute__((ext_vector_type(8)));
typedef short s16x8 __attribute__((ext_vector_type(8)));

__device__ __forceinline__ ushort f2bf(float x) {
  union { float f; unsigned u; } a; a.f = x;
  unsigned r = a.u + 0x7FFFu + ((a.u >> 16) & 1u);  // RNE
  return (ushort)(r >> 16);
}
__device__ __forceinline__ float bf2f(ushort u) {
  union { unsigned u; float f; } a; a.u = (unsigned)u << 16;
  return a.f;
}

__device__ __forceinline__ void gload16(const void* g, void* l) {
  __builtin_amdgcn_global_load_lds(
      (const __attribute__((address_space(1))) void*)g,
      (__attribute__((address_space(3))) void*)l, 16, 0, 0);
}

// ---------------------------------------------------------------------------
// bf16 MFMA GEMM — r19/r21 structure (best measured). Used for routing
// (CSTAT) and dispatch (ATOMIC, long K).
// ---------------------------------------------------------------------------
template <bool ATOMIC, bool OBF, bool CSTAT>
__global__ __launch_bounds__(512) void k_gemm(const ushort* __restrict__ A,
                                              const ushort* __restrict__ Bt,
                                              void* __restrict__ Cv,
                                              int N, int kchunk,
                                              int lda, int ldb,
                                              float* __restrict__ pmOut,
                                              float* __restrict__ pzOut,
                                              float* __restrict__ rpmOut,
                                              float* __restrict__ rpzOut) {
  __shared__ __align__(16) ushort As0[256 * 64];
  __shared__ __align__(16) ushort As1[256 * 64];
  __shared__ __align__(16) ushort As2[256 * 64];
  __shared__ __align__(16) ushort Bs0[128 * 64];
  __shared__ __align__(16) ushort Bs1[128 * 64];
  __shared__ __align__(16) ushort Bs2[128 * 64];

  const int tid = threadIdx.x;
  const int wid = tid >> 6;
  const int lane = tid & 63;

  // T1 XCD-chunked swizzle (bijective: nwg % 8 == 0)
  const int gx = gridDim.x, gy = gridDim.y;
  int wg = (blockIdx.z * gy + blockIdx.y) * gx + blockIdx.x;
  const int nwg = gx * gy * gridDim.z;
  wg = (wg & 7) * (nwg >> 3) + (wg >> 3);
  const int bx = wg % gx;
  const int rest = wg / gx;
  const int by = rest % gy;
  const int bz = rest / gy;

  const int n0 = bx * 128;
  const int m0 = by * 256;
  const int kb = bz * kchunk;

  const int w8 = wid * 8;
  const int lr = lane >> 3;
  const int ks = (((lane & 7) ^ lr) * 8);
  const ushort* Asrc = A + (size_t)(m0 + w8 + lr) * lda + ks;
  const ushort* Bsrc = Bt + (size_t)(n0 + w8 + lr) * ldb + ks;

  const int wm64 = (wid >> 1) * 64;
  const int wn64 = (wid & 1) * 64;
  const int fr = lane & 15;
  const int fq = lane >> 4;
  const int fq8 = fq * 8;
  const int frsw = (fr & 7) << 3;

  f32x4 acc[4][4];
#pragma unroll
  for (int i = 0; i < 4; ++i)
#pragma unroll
    for (int j = 0; j < 4; ++j) acc[i][j] = (f32x4){0.f, 0.f, 0.f, 0.f};

  const int nt = kchunk / 64;

#define STAGE6(An_, Bn_, kt_)                                                    \
  do {                                                                           \
    _Pragma("unroll") for (int q = 0; q < 4; ++q)                                \
      gload16(Asrc + (size_t)(q * 64) * lda + (kt_), (An_) + (q * 64 + w8) * 64);\
    _Pragma("unroll") for (int q = 0; q < 2; ++q)                                \
      gload16(Bsrc + (size_t)(q * 64) * ldb + (kt_), (Bn_) + (q * 64 + w8) * 64);\
  } while (0)

#define LD(B_, r_, h_)                                                          \
  __builtin_bit_cast(bf16x8, *(const s16x8*)((B_) + (size_t)(r_) * 64 +         \
                                             (((h_) * 32 + fq8) ^ frsw)))

#define GBLOCK(Ab_, Bb_, An_, Bn_, tt_)                                         \
  do {                                                                          \
    if ((tt_) + 1 < nt) asm volatile("s_waitcnt vmcnt(6)" ::: "memory");        \
    else                asm volatile("s_waitcnt vmcnt(0)" ::: "memory");        \
    __builtin_amdgcn_sched_barrier(0);                                          \
    __builtin_amdgcn_s_barrier();                                               \
    __builtin_amdgcn_sched_barrier(0);                                          \
    if ((tt_) + 2 < nt) STAGE6(An_, Bn_, kb + ((tt_) + 2) * 64);                \
    bf16x8 bfr_[4][2];                                                          \
    _Pragma("unroll") for (int n = 0; n < 4; ++n) {                             \
      bfr_[n][0] = LD(Bb_, wn64 + n * 16 + fr, 0);                              \
      bfr_[n][1] = LD(Bb_, wn64 + n * 16 + fr, 1);                              \
    }                                                                           \
    _Pragma("unroll") for (int m = 0; m < 4; ++m) {                             \
      bf16x8 a0_ = LD(Ab_, wm64 + m * 16 + fr, 0);                              \
      bf16x8 a1_ = LD(Ab_, wm64 + m * 16 + fr, 1);                              \
      __builtin_amdgcn_s_setprio(1);                                            \
      _Pragma("unroll") for (int n = 0; n < 4; ++n)                             \
        acc[m][n] = __builtin_amdgcn_mfma_f32_16x16x32_bf16(a0_, bfr_[n][0],    \
                                                            acc[m][n], 0, 0, 0);\
      _Pragma("unroll") for (int n = 0; n < 4; ++n)                             \
        acc[m][n] = __builtin_amdgcn_mfma_f32_16x16x32_bf16(a1_, bfr_[n][1],    \
                                                            acc[m][n], 0, 0, 0);\
      __builtin_amdgcn_s_setprio(0);                                            \
    }                                                                           \
  } while (0)

  STAGE6(As0, Bs0, kb);
  STAGE6(As1, Bs1, kb + 64);
  int t = 0;
  for (; t + 3 <= nt; t += 3) {
    GBLOCK(As0, Bs0, As2, Bs2, t);
    GBLOCK(As1, Bs1, As0, Bs0, t + 1);
    GBLOCK(As2, Bs2, As1, Bs1, t + 2);
  }
  if (t < nt) { GBLOCK(As0, Bs0, As2, Bs2, t); ++t; }
  if (t < nt) { GBLOCK(As1, Bs1, As0, Bs0, t); ++t; }
#undef GBLOCK
#undef STAGE6

  // C/D layout: col = lane&15, row = (lane>>4)*4 + reg   [m89-verified]
  if (OBF) {
    ushort* Cb = (ushort*)Cv + (size_t)(m0 + wm64 + fq * 4) * N + n0 + wn64 + fr;
#pragma unroll
    for (int m = 0; m < 4; ++m)
#pragma unroll
      for (int n = 0; n < 4; ++n)
#pragma unroll
        for (int r = 0; r < 4; ++r)
          Cb[(size_t)(m * 16 + r) * N + n * 16] = f2bf(acc[m][n][r]);
  } else {
    float* Cb = (float*)Cv + (size_t)(m0 + wm64 + fq * 4) * N + n0 + wn64 + fr;
#pragma unroll
    for (int m = 0; m < 4; ++m)
#pragma unroll
      for (int n = 0; n < 4; ++n)
#pragma unroll
        for (int r = 0; r < 4; ++r) {
          float* p = Cb + (size_t)(m * 16 + r) * N + n * 16;
          if (ATOMIC) atomicAdd(p, acc[m][n][r]);
          else *p = acc[m][n][r];
        }
  }

  if (CSTAT) {
    float cm_[4], cz_[4];
#pragma unroll
    for (int n = 0; n < 4; ++n) { cm_[n] = -INFINITY; cz_[n] = 0.f; }
#pragma unroll
    for (int m = 0; m < 4; ++m)
#pragma unroll
      for (int n = 0; n < 4; ++n)
#pragma unroll
        for (int r = 0; r < 4; ++r) {
          float v = acc[m][n][r];
          float mm = fmaxf(cm_[n], v);
          cz_[n] = cz_[n] * __expf(cm_[n] - mm) + __expf(v - mm);
          cm_[n] = mm;
        }
#pragma unroll
    for (int off = 16; off <= 32; off <<= 1)
#pragma unroll
      for (int n = 0; n < 4; ++n) {
        float m2 = __shfl_xor(cm_[n], off);
        float z2 = __shfl_xor(cz_[n], off);
        float mm = fmaxf(cm_[n], m2);
        cz_[n] = cz_[n] * __expf(cm_[n] - mm) + z2 * __expf(m2 - mm);
        cm_[n] = mm;
      }
    float rm_[16], rz_[16];
#pragma unroll
    for (int m = 0; m < 4; ++m)
#pragma unroll
      for (int r = 0; r < 4; ++r) {
        const int i = m * 4 + r;
        float mx = fmaxf(fmaxf(acc[m][0][r], acc[m][1][r]),
                         fmaxf(acc[m][2][r], acc[m][3][r]));
        rm_[i] = mx;
        rz_[i] = __expf(acc[m][0][r] - mx) + __expf(acc[m][1][r] - mx) +
                 __expf(acc[m][2][r] - mx) + __expf(acc[m][3][r] - mx);
      }
#pragma unroll
    for (int off = 1; off <= 8; off <<= 1)
#pragma unroll
      for (int i = 0; i < 16; ++i) {
        float m2 = __shfl_xor(rm_[i], off);
        float z2 = __shfl_xor(rz_[i], off);
        float mm = fmaxf(rm_[i], m2);
        rz_[i] = rz_[i] * __expf(rm_[i] - mm) + z2 * __expf(m2 - mm);
        rm_[i] = mm;
      }
    __syncthreads();
    float* smx = (float*)As0;
    float* smz = smx + 4 * 128;
    float* smr = (float*)Bs0;
    float* smz2 = smr + 512;
    const int mrow = wid >> 1;
    if (lane < 16) {
#pragma unroll
      for (int n = 0; n < 4; ++n) {
        smx[mrow * 128 + wn64 + n * 16 + lane] = cm_[n];
        smz[mrow * 128 + wn64 + n * 16 + lane] = cz_[n];
      }
    }
    if (fr == 0) {
#pragma unroll
      for (int m = 0; m < 4; ++m)
#pragma unroll
        for (int r = 0; r < 4; ++r) {
          const int row = wm64 + m * 16 + fq * 4 + r;
          smr[(wid & 1) * 256 + row] = rm_[m * 4 + r];
          smz2[(wid & 1) * 256 + row] = rz_[m * 4 + r];
        }
    }
    __syncthreads();
    if (tid < 128) {
      float m = smx[tid], z = smz[tid];
#pragma unroll
      for (int p = 1; p < 4; ++p) {
        float m2 = smx[p * 128 + tid], z2 = smz[p * 128 + tid];
        float mm = fmaxf(m, m2);
        z = z * __expf(m - mm) + z2 * __expf(m2 - mm);
        m = mm;
      }
      pmOut[(size_t)by * NP + n0 + tid] = m;
      pzOut[(size_t)by * NP + n0 + tid] = z;
    }
    if (tid < 256) {
      float m1 = smr[tid], z1 = smz2[tid];
      float m2 = smr[256 + tid], z2 = smz2[256 + tid];
      float mm = fmaxf(m1, m2);
      float zz = z1 * __expf(m1 - mm) + z2 * __expf(m2 - mm);
      rpmOut[(size_t)bx * BT + m0 + tid] = mm;
      rpzOut[(size_t)bx * BT + m0 + tid] = zz;
    }
  }
#undef LD
}

// ---------------------------------------------------------------------------
// Combine-only GEMM: C[M][N](f32) = A[M][K] @ Bt[N][K]^T with K=512 (nt=8).
// 128x128 tile, BK=64, 8 waves (2M x 4N), 2-buffer ping-pong, 64KB LDS ->
// 2 blocks/CU (vs 1 for the 144KB template): inter-block TLP hides the
// prologue/epilogue tails that dominate at nt=8 (1024 blocks serialized
// 4-deep per CU before). Counted vmcnt(4), one barrier pair per K-tile,
// compile-time buffers via 2x unroll. Same per-output accumulation order
// as the big template -> bit-identical results.
// ---------------------------------------------------------------------------
__global__ __launch_bounds__(512) void k_gemmC(const ushort* __restrict__ A,
                                               const ushort* __restrict__ Bt,
                                               float* __restrict__ C,
                                               int N, int K) {
  __shared__ __align__(16) ushort As0[128 * 64];
  __shared__ __align__(16) ushort Bs0[128 * 64];
  __shared__ __align__(16) ushort As1[128 * 64];
  __shared__ __align__(16) ushort Bs1[128 * 64];
  const int tid = threadIdx.x;
  const int wid = tid >> 6;
  const int lane = tid & 63;

  // T1 XCD-chunked swizzle (nwg = 2048, % 8 == 0)
  const int gx = gridDim.x, gy = gridDim.y;
  int wg = blockIdx.y * gx + blockIdx.x;
  const int nwg = gx * gy;
  wg = (wg & 7) * (nwg >> 3) + (wg >> 3);
  const int bx = wg % gx;
  const int by = wg / gx;
  const int n0 = bx * 128;
  const int m0 = by * 128;

  const int w8 = wid * 8;
  const int lr = lane >> 3;
  const int ks = ((lane & 7) ^ lr) * 8;
  const ushort* Asrc = A + (size_t)(m0 + w8 + lr) * K + ks;
  const ushort* Bsrc = Bt + (size_t)(n0 + w8 + lr) * K + ks;

  const int wm64 = (wid >> 2) * 64;   // 2 M-slices of 64
  const int wn32 = (wid & 3) * 32;    // 4 N-slices of 32
  const int fr = lane & 15;
  const int fq = lane >> 4;
  const int fq8 = fq * 8;
  const int frsw = (fr & 7) << 3;

  f32x4 acc[4][2];
#pragma unroll
  for (int i = 0; i < 4; ++i)
#pragma unroll
    for (int j = 0; j < 2; ++j) acc[i][j] = (f32x4){0.f, 0.f, 0.f, 0.f};

  const int nt = K / 64;  // 8 (even)

#define CSTAGE(An_, Bn_, kt_)                                                   \
  do {                                                                          \
    _Pragma("unroll") for (int q = 0; q < 2; ++q)                               \
      gload16(Asrc + (size_t)(q * 64) * K + (kt_), (An_) + (q * 64 + w8) * 64); \
    _Pragma("unroll") for (int q = 0; q < 2; ++q)                               \
      gload16(Bsrc + (size_t)(q * 64) * K + (kt_), (Bn_) + (q * 64 + w8) * 64); \
  } while (0)

#define CLD(B_, r_, h_)                                                         \
  __builtin_bit_cast(bf16x8, *(const s16x8*)((B_) + (size_t)(r_) * 64 +         \
                                             (((h_) * 32 + fq8) ^ frsw)))

#define CITER(Ab_, Bb_, An_, Bn_, tt_)                                          \
  do {                                                                          \
    if ((tt_) + 1 < nt) {                                                       \
      CSTAGE(An_, Bn_, ((tt_) + 1) * 64);                                       \
      asm volatile("s_waitcnt vmcnt(4)" ::: "memory");                          \
    } else {                                                                    \
      asm volatile("s_waitcnt vmcnt(0)" ::: "memory");                          \
    }                                                                           \
    __builtin_amdgcn_sched_barrier(0);                                          \
    __builtin_amdgcn_s_barrier();                                               \
    __builtin_amdgcn_sched_barrier(0);                                          \
    bf16x8 b_[2][2];                                                            \
    _Pragma("unroll") for (int n = 0; n < 2; ++n) {                             \
      b_[n][0] = CLD(Bb_, wn32 + n * 16 + fr, 0);                               \
      b_[n][1] = CLD(Bb_, wn32 + n * 16 + fr, 1);                               \
    }                                                                           \
    _Pragma("unroll") for (int m = 0; m < 4; ++m) {                             \
      bf16x8 a0_ = CLD(Ab_, wm64 + m * 16 + fr, 0);                             \
      bf16x8 a1_ = CLD(Ab_, wm64 + m * 16 + fr, 1);                             \
      __builtin_amdgcn_s_setprio(1);                                            \
      _Pragma("unroll") for (int n = 0; n < 2; ++n)                             \
        acc[m][n] = __builtin_amdgcn_mfma_f32_16x16x32_bf16(a0_, b_[n][0],      \
                                                            acc[m][n], 0, 0, 0);\
      _Pragma("unroll") for (int n = 0; n < 2; ++n)                             \
        acc[m][n] = __builtin_amdgcn_mfma_f32_16x16x32_bf16(a1_, b_[n][1],      \
                                                            acc[m][n], 0, 0, 0);\
      __builtin_amdgcn_s_setprio(0);                                            \
    }                                                                           \
    __builtin_amdgcn_sched_barrier(0);                                          \
    __builtin_amdgcn_s_barrier();                                               \
  } while (0)

  CSTAGE(As0, Bs0, 0);
  for (int t = 0; t < nt; t += 2) {
    CITER(As0, Bs0, As1, Bs1, t);
    CITER(As1, Bs1, As0, Bs0, t + 1);
  }
#undef CITER
#undef CLD
#undef CSTAGE

  // C/D layout: col = lane&15, row = (lane>>4)*4 + reg
  float* Cb = C + (size_t)(m0 + wm64 + fq * 4) * N + n0 + wn32 + fr;
#pragma unroll
  for (int m = 0; m < 4; ++m)
#pragma unroll
    for (int n = 0; n < 2; ++n)
#pragma unroll
      for (int r = 0; r < 4; ++r)
        Cb[(size_t)(m * 16 + r) * N + n * 16] = acc[m][n][r];
}

// ---------------------------------------------------------------------------
// Merged prep (block-range partition).
// ---------------------------------------------------------------------------
__global__ __launch_bounds__(256) void k_prep(const float* __restrict__ tokens,
                                              const float* __restrict__ em,
                                              const float* __restrict__ b1,
                                              const float* __restrict__ b2,
                                              const float* __restrict__ b3,
                                              ushort* __restrict__ tokens_bf,
                                              ushort* __restrict__ emT,
                                              float* __restrict__ base) {
  __shared__ __align__(16) ushort tT[64][256];
  const int tid = threadIdx.x;
  const int bid = blockIdx.x;
  if (bid < 2048) {
    const size_t n = (size_t)BT * DIM;
    size_t i = ((size_t)bid * 256 + tid) * 8;
    const size_t stride = (size_t)2048 * 256 * 8;
    for (; i < n; i += stride) {
      float4 a = *(const float4*)(tokens + i);
      float4 b = *(const float4*)(tokens + i + 4);
      s16x8 o;
      o[0] = (short)f2bf(a.x); o[1] = (short)f2bf(a.y);
      o[2] = (short)f2bf(a.z); o[3] = (short)f2bf(a.w);
      o[4] = (short)f2bf(b.x); o[5] = (short)f2bf(b.y);
      o[6] = (short)f2bf(b.z); o[7] = (short)f2bf(b.w);
      *(s16x8*)(tokens_bf + i) = o;
    }
  } else if (bid < 2080) {
    const int b = bid - 2048;
    const int r0 = (b >> 3) * 256, c0 = (b & 7) * 64;  // em: [1024][512]
#pragma unroll
    for (int i = 0; i < 16; ++i) {
      const int idx = i * 256 + tid;
      const int r = idx >> 4, c4 = (idx & 15) * 4;
      float4 v = *(const float4*)(em + (size_t)(r0 + r) * NP + c0 + c4);
      ushort u[4] = {f2bf(v.x), f2bf(v.y), f2bf(v.z), f2bf(v.w)};
#pragma unroll
      for (int j = 0; j < 4; ++j)
        tT[c4 + j][r ^ (((c4 + j) & 7) << 3)] = u[j];
    }
    __syncthreads();
#pragma unroll
    for (int i = 0; i < 8; ++i) {
      const int idx = i * 256 + tid;
      const int c = idx >> 5, r8 = (idx & 31) * 8;
      s16x8 o = *(const s16x8*)&tT[c][r8 ^ ((c & 7) << 3)];
      *(s16x8*)(emT + (size_t)(c0 + c) * DIM + r0 + r8) = o;
    }
  } else {
    constexpr size_t XH = (size_t)NP * DIM;
    constexpr size_t H1 = (size_t)NP * HID;
    constexpr size_t TOT4 = (2 * XH + 2 * H1) / 4;
    size_t i = (size_t)(bid - 2080) * 256 + tid;
    for (; i < TOT4; i += (size_t)1024 * 256) {
      const size_t idx = i * 4;
      float4 v;
      if (idx < XH) {
        v = make_float4(0.f, 0.f, 0.f, 0.f);
      } else if (idx < XH + H1) {
        const size_t k = idx - XH;
        v = *(const float4*)(b1 + (k / HID) / NS * HID + k % HID);
      } else if (idx < XH + 2 * H1) {
        const size_t k = idx - XH - H1;
        v = *(const float4*)(b2 + (k / HID) / NS * HID + k % HID);
      } else {
        const size_t k = idx - XH - 2 * H1;
        v = *(const float4*)(b3 + (k / DIM) / NS * DIM + k % DIM);
      }
      *(float4*)(base + idx) = v;
    }
  }
}

// ---------------------------------------------------------------------------
// bf16 [R][C] -> bf16 transposed [C][R]. Tile 256x64, L3-warm reads.
// ---------------------------------------------------------------------------
__global__ __launch_bounds__(256) void k_tpose(const ushort* __restrict__ X,
                                               ushort* __restrict__ Yt,
                                               int Cc, int ldt) {
  __shared__ __align__(16) ushort tT[64][256];
  const int tid = threadIdx.x;
  const int r0 = blockIdx.x * 256, c0 = blockIdx.y * 64;
#pragma unroll
  for (int i = 0; i < 8; ++i) {
    const int idx = i * 256 + tid;
    const int r = idx >> 3, c8 = (idx & 7) * 8;
    s16x8 v = *(const s16x8*)(X + (size_t)(r0 + r) * Cc + c0 + c8);
#pragma unroll
    for (int j = 0; j < 8; ++j)
      tT[c8 + j][r ^ (((c8 + j) & 7) << 3)] = (ushort)v[j];
  }
  __syncthreads();
#pragma unroll
  for (int i = 0; i < 8; ++i) {
    const int idx = i * 256 + tid;
    const int c = idx >> 5, r8 = (idx & 31) * 8;
    s16x8 o = *(const s16x8*)&tT[c][r8 ^ ((c & 7) << 3)];
    *(s16x8*)(Yt + (size_t)(c0 + c) * ldt + r0 + r8) = o;
  }
}

// ---------------------------------------------------------------------------
// fp32 [R][C] -> bf16 transposed (yhat -> yhatT). Tile 256x64.
// ---------------------------------------------------------------------------
__global__ __launch_bounds__(256) void k_cvtT(const float* __restrict__ X,
                                              ushort* __restrict__ Yt,
                                              int Cc, int ldt) {
  __shared__ __align__(16) ushort tT[64][256];
  const int tid = threadIdx.x;
  const int r0 = blockIdx.x * 256, c0 = blockIdx.y * 64;
#pragma unroll
  for (int i = 0; i < 16; ++i) {
    const int idx = i * 256 + tid;
    const int r = idx >> 4, c4 = (idx & 15) * 4;
    float4 v = *(const float4*)(X + (size_t)(r0 + r) * Cc + c0 + c4);
    ushort u[4] = {f2bf(v.x), f2bf(v.y), f2bf(v.z), f2bf(v.w)};
#pragma unroll
    for (int j = 0; j < 4; ++j)
      tT[c4 + j][r ^ (((c4 + j) & 7) << 3)] = u[j];
  }
  __syncthreads();
#pragma unroll
  for (int i = 0; i < 8; ++i) {
    const int idx = i * 256 + tid;
    const int c = idx >> 5, r8 = (idx & 31) * 8;
    s16x8 o = *(const s16x8*)&tT[c][r8 ^ ((c & 7) << 3)];
    *(s16x8*)(Yt + (size_t)(c0 + c) * ldt + r0 + r8) = o;
  }
}

// ---------------------------------------------------------------------------
// Merged probability kernel (block-range partition; both halves read matb).
// ---------------------------------------------------------------------------
__global__ __launch_bounds__(256) void k_probs2(const ushort* __restrict__ mat,
                                                const float* __restrict__ pm,
                                                const float* __restrict__ pz,
                                                const float* __restrict__ rpm,
                                                const float* __restrict__ rpz,
                                                ushort* __restrict__ Pc,
                                                ushort* __restrict__ Pt) {
  __shared__ __align__(16) ushort tT[64][256];
  __shared__ float s0buf[64], s1buf[64];
  __shared__ float sm[4][64], sz[4][64];
  const int tid = threadIdx.x;
  const int bid = blockIdx.x;
  if (bid < BT / 64) {
    const int t0 = bid * 64;
    if (tid < 64) {
      const int t = t0 + tid;
      float m = -INFINITY, z = 0.f;
#pragma unroll
      for (int c = 0; c < 4; ++c) {
        float m2 = rpm[(size_t)c * BT + t], z2 = rpz[(size_t)c * BT + t];
        float mm = fmaxf(m, m2);
        z = z * __expf(m - mm) + z2 * __expf(m2 - mm);
        m = mm;
      }
      s0buf[tid] = m;
      s1buf[tid] = 1.f / z;
    }
    __syncthreads();
#pragma unroll
    for (int i = 0; i < 16; ++i) {
      const int idx = i * 256 + tid;
      const int r = idx >> 6, c8 = (idx & 63) * 8;
      s16x8 v = *(const s16x8*)(mat + (size_t)(t0 + r) * NP + c8);
      const float mr = s0buf[r], zr = s1buf[r];
      s16x8 oc;
#pragma unroll
      for (int j = 0; j < 8; ++j)
        oc[j] = (short)f2bf(__expf(bf2f((ushort)v[j]) - mr) * zr);
      *(s16x8*)(Pc + (size_t)(t0 + r) * NP + c8) = oc;
    }
  } else {
    const int b2 = bid - BT / 64;
    const int t0 = (b2 % (BT / 256)) * 256, s0 = (b2 / (BT / 256)) * 64;
    {
      const int col = s0 + (tid & 63);
      const int q = tid >> 6;
      float m = -INFINITY, z = 0.f;
      for (int r = q; r < BT / 256; r += 4) {
        float m2 = pm[(size_t)r * NP + col], z2 = pz[(size_t)r * NP + col];
        float mm = fmaxf(m, m2);
        z = z * __expf(m - mm) + z2 * __expf(m2 - mm);
        m = mm;
      }
      sm[q][tid & 63] = m;
      sz[q][tid & 63] = z;
    }
    __syncthreads();
    if (tid < 64) {
      float m = sm[0][tid], z = sz[0][tid];
#pragma unroll
      for (int p = 1; p < 4; ++p) {
        float m2 = sm[p][tid], z2 = sz[p][tid];
        float mm = fmaxf(m, m2);
        z = z * __expf(m - mm) + z2 * __expf(m2 - mm);
        m = mm;
      }
      s0buf[tid] = m;
      s1buf[tid] = 1.f / z;
    }
    __syncthreads();
#pragma unroll
    for (int i = 0; i < 8; ++i) {
      const int idx = i * 256 + tid;
      const int r = idx >> 3, c8 = (idx & 7) * 8;
      s16x8 v = *(const s16x8*)(mat + (size_t)(t0 + r) * NP + s0 + c8);
#pragma unroll
      for (int j = 0; j < 8; ++j)
        tT[c8 + j][r ^ (((c8 + j) & 7) << 3)] =
            f2bf(__expf(bf2f((ushort)v[j]) - s0buf[c8 + j]) * s1buf[c8 + j]);
    }
    __syncthreads();
#pragma unroll
    for (int i = 0; i < 8; ++i) {
      const int idx = i * 256 + tid;
      const int c = idx >> 5, r8 = (idx & 31) * 8;
      s16x8 o = *(const s16x8*)&tT[c][r8 ^ ((c & 7) << 3)];
      *(s16x8*)(Pt + (size_t)(s0 + c) * BT + t0 + r8) = o;
    }
  }
}

// ---------------------------------------------------------------------------
// Expert MLP layer, split-K: grid (NE, N/64, KS). Stages 8 x KSL slot-slice
// (consumer-side ReLU), streams W slice, atomicAdds into bias-seeded Y.
// ---------------------------------------------------------------------------
template <int K, int N, int KS, bool RELU_IN>
__global__ __launch_bounds__(256) void k_mlp(const float* __restrict__ X,
                                             const float* __restrict__ W,
                                             float* __restrict__ Y) {
  constexpr int KSL = K / KS;
  __shared__ float xs[NS * KSL];
  const int tid = threadIdx.x;
  const int e = blockIdx.x;
  const int k0 = blockIdx.z * KSL;
  constexpr int T4 = (NS * KSL) / 4;  // float4 chunks to stage
  for (int i = tid; i < T4; i += 256) {
    const int p = i / (KSL / 4), kk4 = (i % (KSL / 4)) * 4;
    float4 v = *(const float4*)(X + (size_t)(e * NS + p) * K + k0 + kk4);
    if (RELU_IN) {
      v.x = fmaxf(v.x, 0.f); v.y = fmaxf(v.y, 0.f);
      v.z = fmaxf(v.z, 0.f); v.w = fmaxf(v.w, 0.f);
    }
    *(float4*)(xs + p * KSL + kk4) = v;
  }
  __syncthreads();
  const int j = blockIdx.y * 64 + (tid & 63);
  const int pr = tid >> 6;  // handles p = pr and p = pr+4
  const float* w = W + (size_t)e * K * N + (size_t)k0 * N + j;
  const float* x0 = xs + pr * KSL;
  const float* x1 = xs + (pr + 4) * KSL;
  float a0 = 0.f, a1 = 0.f;
#pragma unroll 8
  for (int k = 0; k < KSL; ++k) {
    float wv = w[(size_t)k * N];
    a0 += x0[k] * wv;
    a1 += x1[k] * wv;
  }
  atomicAdd(Y + (size_t)(e * NS + pr) * N + j, a0);
  atomicAdd(Y + (size_t)(e * NS + pr + 4) * N + j, a1);
}

}  // namespace

extern "C" void kernel_launch(void* const* d_in, const int* in_sizes, int n_in,
                              void* d_out, int out_size, void* d_ws, size_t ws_size,
                              hipStream_t stream) {
  const float* tokens = (const float*)d_in[0];  // [BT, DIM]
  const float* em     = (const float*)d_in[1];  // [DIM, NP]
  const float* W1     = (const float*)d_in[2];
  const float* b1     = (const float*)d_in[3];
  const float* W2     = (const float*)d_in[4];
  const float* b2     = (const float*)d_in[5];
  const float* W3     = (const float*)d_in[6];
  const float* b3     = (const float*)d_in[7];
  float* out = (float*)d_out;

  char* w = (char*)d_ws;
  ushort* matb      = (ushort*)w; w += (size_t)BT * NP * 2;    // 32MB bf16 logits
  ushort* tokens_bf = (ushort*)w; w += (size_t)BT * DIM * 2;   // 64MB
  ushort* tokT      = (ushort*)w; w += (size_t)DIM * BT * 2;   // 64MB
  ushort* Pt        = (ushort*)w; w += (size_t)NP * BT * 2;    // 33.5MB
  ushort* Pc        = (ushort*)w; w += (size_t)BT * NP * 2;    // 33.5MB
  ushort* emT       = (ushort*)w; w += (size_t)NP * DIM * 2;
  ushort* yhatT     = (ushort*)w; w += (size_t)DIM * NP * 2;
  float*  pm        = (float*)w;  w += (size_t)(BT / 256) * NP * 4;
  float*  pz        = (float*)w;  w += (size_t)(BT / 256) * NP * 4;
  float*  rpm       = (float*)w;  w += (size_t)4 * BT * 4;
  float*  rpz       = (float*)w;  w += (size_t)4 * BT * 4;
  float*  xhat      = (float*)w;  w += (size_t)NP * DIM * 4;   // NOTE: xhat,h1,
  float*  h1        = (float*)w;  w += (size_t)NP * HID * 4;   // h2,yhat must
  float*  h2        = (float*)w;  w += (size_t)NP * HID * 4;   // stay contiguous
  float*  yhat      = (float*)w;  w += (size_t)NP * DIM * 4;   // (k_prep binit)
  (void)ws_size; (void)in_sizes; (void)n_in; (void)out_size;

  // 0. merged prep: tokens convert + em transpose + binit (one launch)
  k_prep<<<3104, 256, 0, stream>>>(tokens, em, b1, b2, b3, tokens_bf, emT, xhat);
  k_tpose<<<dim3(BT / 256, DIM / 64), 256, 0, stream>>>(tokens_bf, tokT, DIM, BT);
  // 1. routing logits (bf16 out) + fused column AND row stat partials
  k_gemm<false, true, true><<<dim3(NP / 128, BT / 256, 1), 512, 0, stream>>>(
      tokens_bf, emT, matb, NP, DIM, DIM, DIM, pm, pz, rpm, rpz);
  // 2. probabilities: Pc + Pt in one launch (block-range partition)
  k_probs2<<<BT / 64 + (BT / 256) * (NP / 64), 256, 0, stream>>>(
      matb, pm, pz, rpm, rpz, Pc, Pt);
  // 3. dispatch: xhat = Pt @ tokens  (split-K 16, fp32 atomics)
  k_gemm<true, false, false><<<dim3(DIM / 128, NP / 256, 16), 512, 0, stream>>>(
      Pt, tokT, xhat, DIM, BT / 16, BT, BT, nullptr, nullptr, nullptr, nullptr);
  // 4. expert MLPs: split-K (8/4/4), consumer-side ReLU
  k_mlp<DIM, HID, 8, false><<<dim3(NE, HID / 64, 8), 256, 0, stream>>>(xhat, W1, h1);
  k_mlp<HID, HID, 4, true><<<dim3(NE, HID / 64, 4), 256, 0, stream>>>(h1, W2, h2);
  k_mlp<HID, DIM, 4, true><<<dim3(NE, DIM / 64, 4), 256, 0, stream>>>(h2, W3, yhat);
  k_cvtT<<<dim3(NP / 256, DIM / 64), 256, 0, stream>>>(yhat, yhatT, DIM, NP);
  // 5. combine: out = Pc @ yhat  (128x128 2-blocks/CU variant, K=512)
  k_gemmC<<<dim3(DIM / 128, BT / 128), 512, 0, stream>>>(Pc, yhatT, out, DIM, NP);
}

// Round 23
// 323.310 us; speedup vs baseline: 1.0062x; 1.0062x over previous
//
#include <hip/hip_runtime.h>
#include <math.h>

namespace {

constexpr int BT  = 8 * 4096;   // 32768 tokens
constexpr int DIM = 1024;       // model dim
constexpr int NE  = 64;         // experts
constexpr int NS  = 8;          // slots per expert
constexpr int NP  = NE * NS;    // 512 total slots
constexpr int HID = 256;

typedef float f32x4 __attribute__((ext_vector_type(4)));
typedef __bf16 bf16x8 __attribute__((ext_vector_type(8)));
typedef short s16x8 __attribute__((ext_vector_type(8)));

__device__ __forceinline__ ushort f2bf(float x) {
  union { float f; unsigned u; } a; a.f = x;
  unsigned r = a.u + 0x7FFFu + ((a.u >> 16) & 1u);  // RNE
  return (ushort)(r >> 16);
}
__device__ __forceinline__ float bf2f(ushort u) {
  union { unsigned u; float f; } a; a.u = (unsigned)u << 16;
  return a.f;
}

__device__ __forceinline__ void gload16(const void* g, void* l) {
  __builtin_amdgcn_global_load_lds(
      (const __attribute__((address_space(1))) void*)g,
      (__attribute__((address_space(3))) void*)l, 16, 0, 0);
}

// ---------------------------------------------------------------------------
// bf16 MFMA GEMM — r19/r21 structure (best measured; r22's 2-blocks/CU
// combine variant was null). Serves routing (CSTAT), dispatch (ATOMIC),
// and combine (plain fp32-out).
// ---------------------------------------------------------------------------
template <bool ATOMIC, bool OBF, bool CSTAT>
__global__ __launch_bounds__(512) void k_gemm(const ushort* __restrict__ A,
                                              const ushort* __restrict__ Bt,
                                              void* __restrict__ Cv,
                                              int N, int kchunk,
                                              int lda, int ldb,
                                              float* __restrict__ pmOut,
                                              float* __restrict__ pzOut,
                                              float* __restrict__ rpmOut,
                                              float* __restrict__ rpzOut) {
  __shared__ __align__(16) ushort As0[256 * 64];
  __shared__ __align__(16) ushort As1[256 * 64];
  __shared__ __align__(16) ushort As2[256 * 64];
  __shared__ __align__(16) ushort Bs0[128 * 64];
  __shared__ __align__(16) ushort Bs1[128 * 64];
  __shared__ __align__(16) ushort Bs2[128 * 64];

  const int tid = threadIdx.x;
  const int wid = tid >> 6;
  const int lane = tid & 63;

  // T1 XCD-chunked swizzle (bijective: nwg % 8 == 0)
  const int gx = gridDim.x, gy = gridDim.y;
  int wg = (blockIdx.z * gy + blockIdx.y) * gx + blockIdx.x;
  const int nwg = gx * gy * gridDim.z;
  wg = (wg & 7) * (nwg >> 3) + (wg >> 3);
  const int bx = wg % gx;
  const int rest = wg / gx;
  const int by = rest % gy;
  const int bz = rest / gy;

  const int n0 = bx * 128;
  const int m0 = by * 256;
  const int kb = bz * kchunk;

  const int w8 = wid * 8;
  const int lr = lane >> 3;
  const int ks = (((lane & 7) ^ lr) * 8);
  const ushort* Asrc = A + (size_t)(m0 + w8 + lr) * lda + ks;
  const ushort* Bsrc = Bt + (size_t)(n0 + w8 + lr) * ldb + ks;

  const int wm64 = (wid >> 1) * 64;
  const int wn64 = (wid & 1) * 64;
  const int fr = lane & 15;
  const int fq = lane >> 4;
  const int fq8 = fq * 8;
  const int frsw = (fr & 7) << 3;

  f32x4 acc[4][4];
#pragma unroll
  for (int i = 0; i < 4; ++i)
#pragma unroll
    for (int j = 0; j < 4; ++j) acc[i][j] = (f32x4){0.f, 0.f, 0.f, 0.f};

  const int nt = kchunk / 64;

#define STAGE6(An_, Bn_, kt_)                                                    \
  do {                                                                           \
    _Pragma("unroll") for (int q = 0; q < 4; ++q)                                \
      gload16(Asrc + (size_t)(q * 64) * lda + (kt_), (An_) + (q * 64 + w8) * 64);\
    _Pragma("unroll") for (int q = 0; q < 2; ++q)                                \
      gload16(Bsrc + (size_t)(q * 64) * ldb + (kt_), (Bn_) + (q * 64 + w8) * 64);\
  } while (0)

#define LD(B_, r_, h_)                                                          \
  __builtin_bit_cast(bf16x8, *(const s16x8*)((B_) + (size_t)(r_) * 64 +         \
                                             (((h_) * 32 + fq8) ^ frsw)))

#define GBLOCK(Ab_, Bb_, An_, Bn_, tt_)                                         \
  do {                                                                          \
    if ((tt_) + 1 < nt) asm volatile("s_waitcnt vmcnt(6)" ::: "memory");        \
    else                asm volatile("s_waitcnt vmcnt(0)" ::: "memory");        \
    __builtin_amdgcn_sched_barrier(0);                                          \
    __builtin_amdgcn_s_barrier();                                               \
    __builtin_amdgcn_sched_barrier(0);                                          \
    if ((tt_) + 2 < nt) STAGE6(An_, Bn_, kb + ((tt_) + 2) * 64);                \
    bf16x8 bfr_[4][2];                                                          \
    _Pragma("unroll") for (int n = 0; n < 4; ++n) {                             \
      bfr_[n][0] = LD(Bb_, wn64 + n * 16 + fr, 0);                              \
      bfr_[n][1] = LD(Bb_, wn64 + n * 16 + fr, 1);                              \
    }                                                                           \
    _Pragma("unroll") for (int m = 0; m < 4; ++m) {                             \
      bf16x8 a0_ = LD(Ab_, wm64 + m * 16 + fr, 0);                              \
      bf16x8 a1_ = LD(Ab_, wm64 + m * 16 + fr, 1);                              \
      __builtin_amdgcn_s_setprio(1);                                            \
      _Pragma("unroll") for (int n = 0; n < 4; ++n)                             \
        acc[m][n] = __builtin_amdgcn_mfma_f32_16x16x32_bf16(a0_, bfr_[n][0],    \
                                                            acc[m][n], 0, 0, 0);\
      _Pragma("unroll") for (int n = 0; n < 4; ++n)                             \
        acc[m][n] = __builtin_amdgcn_mfma_f32_16x16x32_bf16(a1_, bfr_[n][1],    \
                                                            acc[m][n], 0, 0, 0);\
      __builtin_amdgcn_s_setprio(0);                                            \
    }                                                                           \
  } while (0)

  STAGE6(As0, Bs0, kb);
  STAGE6(As1, Bs1, kb + 64);
  int t = 0;
  for (; t + 3 <= nt; t += 3) {
    GBLOCK(As0, Bs0, As2, Bs2, t);
    GBLOCK(As1, Bs1, As0, Bs0, t + 1);
    GBLOCK(As2, Bs2, As1, Bs1, t + 2);
  }
  if (t < nt) { GBLOCK(As0, Bs0, As2, Bs2, t); ++t; }
  if (t < nt) { GBLOCK(As1, Bs1, As0, Bs0, t); ++t; }
#undef GBLOCK
#undef STAGE6

  // C/D layout: col = lane&15, row = (lane>>4)*4 + reg   [m89-verified]
  if (OBF) {
    ushort* Cb = (ushort*)Cv + (size_t)(m0 + wm64 + fq * 4) * N + n0 + wn64 + fr;
#pragma unroll
    for (int m = 0; m < 4; ++m)
#pragma unroll
      for (int n = 0; n < 4; ++n)
#pragma unroll
        for (int r = 0; r < 4; ++r)
          Cb[(size_t)(m * 16 + r) * N + n * 16] = f2bf(acc[m][n][r]);
  } else {
    float* Cb = (float*)Cv + (size_t)(m0 + wm64 + fq * 4) * N + n0 + wn64 + fr;
#pragma unroll
    for (int m = 0; m < 4; ++m)
#pragma unroll
      for (int n = 0; n < 4; ++n)
#pragma unroll
        for (int r = 0; r < 4; ++r) {
          float* p = Cb + (size_t)(m * 16 + r) * N + n * 16;
          if (ATOMIC) atomicAdd(p, acc[m][n][r]);
          else *p = acc[m][n][r];
        }
  }

  if (CSTAT) {
    float cm_[4], cz_[4];
#pragma unroll
    for (int n = 0; n < 4; ++n) { cm_[n] = -INFINITY; cz_[n] = 0.f; }
#pragma unroll
    for (int m = 0; m < 4; ++m)
#pragma unroll
      for (int n = 0; n < 4; ++n)
#pragma unroll
        for (int r = 0; r < 4; ++r) {
          float v = acc[m][n][r];
          float mm = fmaxf(cm_[n], v);
          cz_[n] = cz_[n] * __expf(cm_[n] - mm) + __expf(v - mm);
          cm_[n] = mm;
        }
#pragma unroll
    for (int off = 16; off <= 32; off <<= 1)
#pragma unroll
      for (int n = 0; n < 4; ++n) {
        float m2 = __shfl_xor(cm_[n], off);
        float z2 = __shfl_xor(cz_[n], off);
        float mm = fmaxf(cm_[n], m2);
        cz_[n] = cz_[n] * __expf(cm_[n] - mm) + z2 * __expf(m2 - mm);
        cm_[n] = mm;
      }
    float rm_[16], rz_[16];
#pragma unroll
    for (int m = 0; m < 4; ++m)
#pragma unroll
      for (int r = 0; r < 4; ++r) {
        const int i = m * 4 + r;
        float mx = fmaxf(fmaxf(acc[m][0][r], acc[m][1][r]),
                         fmaxf(acc[m][2][r], acc[m][3][r]));
        rm_[i] = mx;
        rz_[i] = __expf(acc[m][0][r] - mx) + __expf(acc[m][1][r] - mx) +
                 __expf(acc[m][2][r] - mx) + __expf(acc[m][3][r] - mx);
      }
#pragma unroll
    for (int off = 1; off <= 8; off <<= 1)
#pragma unroll
      for (int i = 0; i < 16; ++i) {
        float m2 = __shfl_xor(rm_[i], off);
        float z2 = __shfl_xor(rz_[i], off);
        float mm = fmaxf(rm_[i], m2);
        rz_[i] = rz_[i] * __expf(rm_[i] - mm) + z2 * __expf(m2 - mm);
        rm_[i] = mm;
      }
    __syncthreads();
    float* smx = (float*)As0;
    float* smz = smx + 4 * 128;
    float* smr = (float*)Bs0;
    float* smz2 = smr + 512;
    const int mrow = wid >> 1;
    if (lane < 16) {
#pragma unroll
      for (int n = 0; n < 4; ++n) {
        smx[mrow * 128 + wn64 + n * 16 + lane] = cm_[n];
        smz[mrow * 128 + wn64 + n * 16 + lane] = cz_[n];
      }
    }
    if (fr == 0) {
#pragma unroll
      for (int m = 0; m < 4; ++m)
#pragma unroll
        for (int r = 0; r < 4; ++r) {
          const int row = wm64 + m * 16 + fq * 4 + r;
          smr[(wid & 1) * 256 + row] = rm_[m * 4 + r];
          smz2[(wid & 1) * 256 + row] = rz_[m * 4 + r];
        }
    }
    __syncthreads();
    if (tid < 128) {
      float m = smx[tid], z = smz[tid];
#pragma unroll
      for (int p = 1; p < 4; ++p) {
        float m2 = smx[p * 128 + tid], z2 = smz[p * 128 + tid];
        float mm = fmaxf(m, m2);
        z = z * __expf(m - mm) + z2 * __expf(m2 - mm);
        m = mm;
      }
      pmOut[(size_t)by * NP + n0 + tid] = m;
      pzOut[(size_t)by * NP + n0 + tid] = z;
    }
    if (tid < 256) {
      float m1 = smr[tid], z1 = smz2[tid];
      float m2 = smr[256 + tid], z2 = smz2[256 + tid];
      float mm = fmaxf(m1, m2);
      float zz = z1 * __expf(m1 - mm) + z2 * __expf(m2 - mm);
      rpmOut[(size_t)bx * BT + m0 + tid] = mm;
      rpzOut[(size_t)bx * BT + m0 + tid] = zz;
    }
  }
#undef LD
}

// ---------------------------------------------------------------------------
// Merged prep (block-range partition):
//   [0, 2048)       : fp32 tokens -> bf16 rowmajor (grid-stride memcpy-cast)
//   [2048, 2080)    : em fp32 [DIM][NP] -> emT bf16 [NP][DIM] (32 tiles)
//   [2080, 3104)    : zero xhat + bias-seed h1/h2/yhat (float4 grid-stride)
// ---------------------------------------------------------------------------
__global__ __launch_bounds__(256) void k_prep(const float* __restrict__ tokens,
                                              const float* __restrict__ em,
                                              const float* __restrict__ b1,
                                              const float* __restrict__ b2,
                                              const float* __restrict__ b3,
                                              ushort* __restrict__ tokens_bf,
                                              ushort* __restrict__ emT,
                                              float* __restrict__ base) {
  __shared__ __align__(16) ushort tT[64][256];
  const int tid = threadIdx.x;
  const int bid = blockIdx.x;
  if (bid < 2048) {
    const size_t n = (size_t)BT * DIM;
    size_t i = ((size_t)bid * 256 + tid) * 8;
    const size_t stride = (size_t)2048 * 256 * 8;
    for (; i < n; i += stride) {
      float4 a = *(const float4*)(tokens + i);
      float4 b = *(const float4*)(tokens + i + 4);
      s16x8 o;
      o[0] = (short)f2bf(a.x); o[1] = (short)f2bf(a.y);
      o[2] = (short)f2bf(a.z); o[3] = (short)f2bf(a.w);
      o[4] = (short)f2bf(b.x); o[5] = (short)f2bf(b.y);
      o[6] = (short)f2bf(b.z); o[7] = (short)f2bf(b.w);
      *(s16x8*)(tokens_bf + i) = o;
    }
  } else if (bid < 2080) {
    const int b = bid - 2048;
    const int r0 = (b >> 3) * 256, c0 = (b & 7) * 64;  // em: [1024][512]
#pragma unroll
    for (int i = 0; i < 16; ++i) {
      const int idx = i * 256 + tid;
      const int r = idx >> 4, c4 = (idx & 15) * 4;
      float4 v = *(const float4*)(em + (size_t)(r0 + r) * NP + c0 + c4);
      ushort u[4] = {f2bf(v.x), f2bf(v.y), f2bf(v.z), f2bf(v.w)};
#pragma unroll
      for (int j = 0; j < 4; ++j)
        tT[c4 + j][r ^ (((c4 + j) & 7) << 3)] = u[j];
    }
    __syncthreads();
#pragma unroll
    for (int i = 0; i < 8; ++i) {
      const int idx = i * 256 + tid;
      const int c = idx >> 5, r8 = (idx & 31) * 8;
      s16x8 o = *(const s16x8*)&tT[c][r8 ^ ((c & 7) << 3)];
      *(s16x8*)(emT + (size_t)(c0 + c) * DIM + r0 + r8) = o;
    }
  } else {
    constexpr size_t XH = (size_t)NP * DIM;
    constexpr size_t H1 = (size_t)NP * HID;
    constexpr size_t TOT4 = (2 * XH + 2 * H1) / 4;
    size_t i = (size_t)(bid - 2080) * 256 + tid;
    for (; i < TOT4; i += (size_t)1024 * 256) {
      const size_t idx = i * 4;
      float4 v;
      if (idx < XH) {
        v = make_float4(0.f, 0.f, 0.f, 0.f);
      } else if (idx < XH + H1) {
        const size_t k = idx - XH;
        v = *(const float4*)(b1 + (k / HID) / NS * HID + k % HID);
      } else if (idx < XH + 2 * H1) {
        const size_t k = idx - XH - H1;
        v = *(const float4*)(b2 + (k / HID) / NS * HID + k % HID);
      } else {
        const size_t k = idx - XH - 2 * H1;
        v = *(const float4*)(b3 + (k / DIM) / NS * DIM + k % DIM);
      }
      *(float4*)(base + idx) = v;
    }
  }
}

// ---------------------------------------------------------------------------
// bf16 [R][C] -> bf16 transposed [C][R]. Tile 256x64, L3-warm reads.
// ---------------------------------------------------------------------------
__global__ __launch_bounds__(256) void k_tpose(const ushort* __restrict__ X,
                                               ushort* __restrict__ Yt,
                                               int Cc, int ldt) {
  __shared__ __align__(16) ushort tT[64][256];
  const int tid = threadIdx.x;
  const int r0 = blockIdx.x * 256, c0 = blockIdx.y * 64;
#pragma unroll
  for (int i = 0; i < 8; ++i) {
    const int idx = i * 256 + tid;
    const int r = idx >> 3, c8 = (idx & 7) * 8;
    s16x8 v = *(const s16x8*)(X + (size_t)(r0 + r) * Cc + c0 + c8);
#pragma unroll
    for (int j = 0; j < 8; ++j)
      tT[c8 + j][r ^ (((c8 + j) & 7) << 3)] = (ushort)v[j];
  }
  __syncthreads();
#pragma unroll
  for (int i = 0; i < 8; ++i) {
    const int idx = i * 256 + tid;
    const int c = idx >> 5, r8 = (idx & 31) * 8;
    s16x8 o = *(const s16x8*)&tT[c][r8 ^ ((c & 7) << 3)];
    *(s16x8*)(Yt + (size_t)(c0 + c) * ldt + r0 + r8) = o;
  }
}

// ---------------------------------------------------------------------------
// fp32 [R][C] -> bf16 transposed (yhat -> yhatT). Tile 256x64.
// ---------------------------------------------------------------------------
__global__ __launch_bounds__(256) void k_cvtT(const float* __restrict__ X,
                                              ushort* __restrict__ Yt,
                                              int Cc, int ldt) {
  __shared__ __align__(16) ushort tT[64][256];
  const int tid = threadIdx.x;
  const int r0 = blockIdx.x * 256, c0 = blockIdx.y * 64;
#pragma unroll
  for (int i = 0; i < 16; ++i) {
    const int idx = i * 256 + tid;
    const int r = idx >> 4, c4 = (idx & 15) * 4;
    float4 v = *(const float4*)(X + (size_t)(r0 + r) * Cc + c0 + c4);
    ushort u[4] = {f2bf(v.x), f2bf(v.y), f2bf(v.z), f2bf(v.w)};
#pragma unroll
    for (int j = 0; j < 4; ++j)
      tT[c4 + j][r ^ (((c4 + j) & 7) << 3)] = u[j];
  }
  __syncthreads();
#pragma unroll
  for (int i = 0; i < 8; ++i) {
    const int idx = i * 256 + tid;
    const int c = idx >> 5, r8 = (idx & 31) * 8;
    s16x8 o = *(const s16x8*)&tT[c][r8 ^ ((c & 7) << 3)];
    *(s16x8*)(Yt + (size_t)(c0 + c) * ldt + r0 + r8) = o;
  }
}

// ---------------------------------------------------------------------------
// Merged probability kernel (block-range partition; both halves read matb).
// ---------------------------------------------------------------------------
__global__ __launch_bounds__(256) void k_probs2(const ushort* __restrict__ mat,
                                                const float* __restrict__ pm,
                                                const float* __restrict__ pz,
                                                const float* __restrict__ rpm,
                                                const float* __restrict__ rpz,
                                                ushort* __restrict__ Pc,
                                                ushort* __restrict__ Pt) {
  __shared__ __align__(16) ushort tT[64][256];
  __shared__ float s0buf[64], s1buf[64];
  __shared__ float sm[4][64], sz[4][64];
  const int tid = threadIdx.x;
  const int bid = blockIdx.x;
  if (bid < BT / 64) {
    const int t0 = bid * 64;
    if (tid < 64) {
      const int t = t0 + tid;
      float m = -INFINITY, z = 0.f;
#pragma unroll
      for (int c = 0; c < 4; ++c) {
        float m2 = rpm[(size_t)c * BT + t], z2 = rpz[(size_t)c * BT + t];
        float mm = fmaxf(m, m2);
        z = z * __expf(m - mm) + z2 * __expf(m2 - mm);
        m = mm;
      }
      s0buf[tid] = m;
      s1buf[tid] = 1.f / z;
    }
    __syncthreads();
#pragma unroll
    for (int i = 0; i < 16; ++i) {
      const int idx = i * 256 + tid;
      const int r = idx >> 6, c8 = (idx & 63) * 8;
      s16x8 v = *(const s16x8*)(mat + (size_t)(t0 + r) * NP + c8);
      const float mr = s0buf[r], zr = s1buf[r];
      s16x8 oc;
#pragma unroll
      for (int j = 0; j < 8; ++j)
        oc[j] = (short)f2bf(__expf(bf2f((ushort)v[j]) - mr) * zr);
      *(s16x8*)(Pc + (size_t)(t0 + r) * NP + c8) = oc;
    }
  } else {
    const int b2 = bid - BT / 64;
    const int t0 = (b2 % (BT / 256)) * 256, s0 = (b2 / (BT / 256)) * 64;
    {
      const int col = s0 + (tid & 63);
      const int q = tid >> 6;
      float m = -INFINITY, z = 0.f;
      for (int r = q; r < BT / 256; r += 4) {
        float m2 = pm[(size_t)r * NP + col], z2 = pz[(size_t)r * NP + col];
        float mm = fmaxf(m, m2);
        z = z * __expf(m - mm) + z2 * __expf(m2 - mm);
        m = mm;
      }
      sm[q][tid & 63] = m;
      sz[q][tid & 63] = z;
    }
    __syncthreads();
    if (tid < 64) {
      float m = sm[0][tid], z = sz[0][tid];
#pragma unroll
      for (int p = 1; p < 4; ++p) {
        float m2 = sm[p][tid], z2 = sz[p][tid];
        float mm = fmaxf(m, m2);
        z = z * __expf(m - mm) + z2 * __expf(m2 - mm);
        m = mm;
      }
      s0buf[tid] = m;
      s1buf[tid] = 1.f / z;
    }
    __syncthreads();
#pragma unroll
    for (int i = 0; i < 8; ++i) {
      const int idx = i * 256 + tid;
      const int r = idx >> 3, c8 = (idx & 7) * 8;
      s16x8 v = *(const s16x8*)(mat + (size_t)(t0 + r) * NP + s0 + c8);
#pragma unroll
      for (int j = 0; j < 8; ++j)
        tT[c8 + j][r ^ (((c8 + j) & 7) << 3)] =
            f2bf(__expf(bf2f((ushort)v[j]) - s0buf[c8 + j]) * s1buf[c8 + j]);
    }
    __syncthreads();
#pragma unroll
    for (int i = 0; i < 8; ++i) {
      const int idx = i * 256 + tid;
      const int c = idx >> 5, r8 = (idx & 31) * 8;
      s16x8 o = *(const s16x8*)&tT[c][r8 ^ ((c & 7) << 3)];
      *(s16x8*)(Pt + (size_t)(s0 + c) * BT + t0 + r8) = o;
    }
  }
}

// ---------------------------------------------------------------------------
// Expert MLP layer, split-K: grid (NE, N/64, KS). Stages 8 x KSL slot-slice
// (consumer-side ReLU), streams W slice, atomicAdds into bias-seeded Y.
// ---------------------------------------------------------------------------
template <int K, int N, int KS, bool RELU_IN>
__global__ __launch_bounds__(256) void k_mlp(const float* __restrict__ X,
                                             const float* __restrict__ W,
                                             float* __restrict__ Y) {
  constexpr int KSL = K / KS;
  __shared__ float xs[NS * KSL];
  const int tid = threadIdx.x;
  const int e = blockIdx.x;
  const int k0 = blockIdx.z * KSL;
  constexpr int T4 = (NS * KSL) / 4;  // float4 chunks to stage
  for (int i = tid; i < T4; i += 256) {
    const int p = i / (KSL / 4), kk4 = (i % (KSL / 4)) * 4;
    float4 v = *(const float4*)(X + (size_t)(e * NS + p) * K + k0 + kk4);
    if (RELU_IN) {
      v.x = fmaxf(v.x, 0.f); v.y = fmaxf(v.y, 0.f);
      v.z = fmaxf(v.z, 0.f); v.w = fmaxf(v.w, 0.f);
    }
    *(float4*)(xs + p * KSL + kk4) = v;
  }
  __syncthreads();
  const int j = blockIdx.y * 64 + (tid & 63);
  const int pr = tid >> 6;  // handles p = pr and p = pr+4
  const float* w = W + (size_t)e * K * N + (size_t)k0 * N + j;
  const float* x0 = xs + pr * KSL;
  const float* x1 = xs + (pr + 4) * KSL;
  float a0 = 0.f, a1 = 0.f;
#pragma unroll 8
  for (int k = 0; k < KSL; ++k) {
    float wv = w[(size_t)k * N];
    a0 += x0[k] * wv;
    a1 += x1[k] * wv;
  }
  atomicAdd(Y + (size_t)(e * NS + pr) * N + j, a0);
  atomicAdd(Y + (size_t)(e * NS + pr + 4) * N + j, a1);
}

}  // namespace

extern "C" void kernel_launch(void* const* d_in, const int* in_sizes, int n_in,
                              void* d_out, int out_size, void* d_ws, size_t ws_size,
                              hipStream_t stream) {
  const float* tokens = (const float*)d_in[0];  // [BT, DIM]
  const float* em     = (const float*)d_in[1];  // [DIM, NP]
  const float* W1     = (const float*)d_in[2];
  const float* b1     = (const float*)d_in[3];
  const float* W2     = (const float*)d_in[4];
  const float* b2     = (const float*)d_in[5];
  const float* W3     = (const float*)d_in[6];
  const float* b3     = (const float*)d_in[7];
  float* out = (float*)d_out;

  char* w = (char*)d_ws;
  ushort* matb      = (ushort*)w; w += (size_t)BT * NP * 2;    // 32MB bf16 logits
  ushort* tokens_bf = (ushort*)w; w += (size_t)BT * DIM * 2;   // 64MB
  ushort* tokT      = (ushort*)w; w += (size_t)DIM * BT * 2;   // 64MB
  ushort* Pt        = (ushort*)w; w += (size_t)NP * BT * 2;    // 33.5MB
  ushort* Pc        = (ushort*)w; w += (size_t)BT * NP * 2;    // 33.5MB
  ushort* emT       = (ushort*)w; w += (size_t)NP * DIM * 2;
  ushort* yhatT     = (ushort*)w; w += (size_t)DIM * NP * 2;
  float*  pm        = (float*)w;  w += (size_t)(BT / 256) * NP * 4;
  float*  pz        = (float*)w;  w += (size_t)(BT / 256) * NP * 4;
  float*  rpm       = (float*)w;  w += (size_t)4 * BT * 4;
  float*  rpz       = (float*)w;  w += (size_t)4 * BT * 4;
  float*  xhat      = (float*)w;  w += (size_t)NP * DIM * 4;   // NOTE: xhat,h1,
  float*  h1        = (float*)w;  w += (size_t)NP * HID * 4;   // h2,yhat must
  float*  h2        = (float*)w;  w += (size_t)NP * HID * 4;   // stay contiguous
  float*  yhat      = (float*)w;  w += (size_t)NP * DIM * 4;   // (k_prep binit)
  (void)ws_size; (void)in_sizes; (void)n_in; (void)out_size;

  // 0. merged prep: tokens convert + em transpose + binit (one launch)
  k_prep<<<3104, 256, 0, stream>>>(tokens, em, b1, b2, b3, tokens_bf, emT, xhat);
  k_tpose<<<dim3(BT / 256, DIM / 64), 256, 0, stream>>>(tokens_bf, tokT, DIM, BT);
  // 1. routing logits (bf16 out) + fused column AND row stat partials
  k_gemm<false, true, true><<<dim3(NP / 128, BT / 256, 1), 512, 0, stream>>>(
      tokens_bf, emT, matb, NP, DIM, DIM, DIM, pm, pz, rpm, rpz);
  // 2. probabilities: Pc + Pt in one launch (block-range partition)
  k_probs2<<<BT / 64 + (BT / 256) * (NP / 64), 256, 0, stream>>>(
      matb, pm, pz, rpm, rpz, Pc, Pt);
  // 3. dispatch: xhat = Pt @ tokens  (split-K 16, fp32 atomics)
  k_gemm<true, false, false><<<dim3(DIM / 128, NP / 256, 16), 512, 0, stream>>>(
      Pt, tokT, xhat, DIM, BT / 16, BT, BT, nullptr, nullptr, nullptr, nullptr);
  // 4. expert MLPs: split-K (8/4/4), consumer-side ReLU
  k_mlp<DIM, HID, 8, false><<<dim3(NE, HID / 64, 8), 256, 0, stream>>>(xhat, W1, h1);
  k_mlp<HID, HID, 4, true><<<dim3(NE, HID / 64, 4), 256, 0, stream>>>(h1, W2, h2);
  k_mlp<HID, DIM, 4, true><<<dim3(NE, DIM / 64, 4), 256, 0, stream>>>(h2, W3, yhat);
  k_cvtT<<<dim3(NP / 256, DIM / 64), 256, 0, stream>>>(yhat, yhatT, DIM, NP);
  // 5. combine: out = Pc @ yhat  (big 3-buf template, r21 best config)
  k_gemm<false, false, false><<<dim3(DIM / 128, BT / 256, 1), 512, 0, stream>>>(
      Pc, yhatT, out, DIM, NP, NP, NP, nullptr, nullptr, nullptr, nullptr);
}